// Round 2
// baseline (578.069 us; speedup 1.0000x reference)
//
#include <hip/hip_runtime.h>
#include <math.h>

#define NN 50000
#define EE 800000
#define FIN 128
#define NH 5
#define HC 160
#define NG 64
#define CH 128        // fast-path max items per node (deg <= 127)
#define NB 160        // sort blocks
#define EPB 5000      // edges per sort block (NB*EPB == EE)
#define NW 12500      // packed histogram words (4 byte-bins per word)
#define ALS8 8        // padded stride for al_s (float4 + float loads)

__device__ __forceinline__ float lrelu(float x, float s) { return x >= 0.f ? x : s * x; }

// ---------------- psum zero + per-graph node counts via binary search (batch sorted)
__global__ void prep_kernel(const int* __restrict__ batch, float* psum, int* gcnt) {
    int i = blockIdx.x * 256 + threadIdx.x;
    if (i < NG * HC) psum[i] = 0.f;
    if (i < NG) {
        int lo = 0, hi = NN;
        while (lo < hi) { int m = (lo + hi) >> 1; if (batch[m] < i) lo = m + 1; else hi = m; }
        int s = lo;
        lo = 0; hi = NN;
        int g1 = i + 1;
        while (lo < hi) { int m = (lo + hi) >> 1; if (batch[m] < g1) lo = m + 1; else hi = m; }
        gcnt[i] = lo - s;
    }
}

// ---------------- per-block LDS histogram of dst (byte-packed, no global atomics)
__global__ __launch_bounds__(256) void hist_kernel(const int* __restrict__ ei,
                                                   unsigned* __restrict__ hist_g) {
    __shared__ unsigned lh[NW];
    int b = blockIdx.x, tid = threadIdx.x;
    for (int w = tid; w < NW; w += 256) lh[w] = 0;
    __syncthreads();
    const int* dstp = ei + EE + b * EPB;
    for (int i = tid; i < EPB; i += 256) {
        int d = dstp[i];
        atomicAdd(&lh[d >> 2], 1u << ((d & 3) * 8));
    }
    __syncthreads();
    unsigned* outp = hist_g + (size_t)b * NW;
    for (int w = tid; w < NW; w += 256) outp[w] = lh[w];
}

// ---------------- column scan over blocks: per-(block,bin) base + total deg
__global__ void sscan_kernel(const unsigned* __restrict__ hist_g,
                             unsigned short* __restrict__ base_g, int* __restrict__ deg) {
    int w = blockIdx.x * 256 + threadIdx.x;
    if (w >= NW) return;
    unsigned r0 = 0, r1 = 0, r2 = 0, r3 = 0;
    for (int b = 0; b < NB; b++) {
        unsigned x = hist_g[(size_t)b * NW + w];
        uint2 st;
        st.x = r0 | (r1 << 16);
        st.y = r2 | (r3 << 16);
        *reinterpret_cast<uint2*>(&base_g[(size_t)b * NN + 4 * w]) = st;
        r0 += x & 0xffu; r1 += (x >> 8) & 0xffu; r2 += (x >> 16) & 0xffu; r3 += (x >> 24) & 0xffu;
    }
    uint4 dv; dv.x = r0; dv.y = r1; dv.z = r2; dv.w = r3;
    *reinterpret_cast<uint4*>(&deg[4 * w]) = dv;
}

// ------------------------------------------------------- 3-phase parallel scan
__global__ void scan1_kernel(const int* __restrict__ deg, int* bsum) {
    __shared__ int ws[4];
    int tid = threadIdx.x, lane = tid & 63, wid = tid >> 6;
    int i = blockIdx.x * 256 + tid;
    int v = (i < NN) ? deg[i] : 0;
    for (int o = 32; o >= 1; o >>= 1) v += __shfl_down(v, o, 64);
    if (lane == 0) ws[wid] = v;
    __syncthreads();
    if (tid == 0) bsum[blockIdx.x] = ws[0] + ws[1] + ws[2] + ws[3];
}

__global__ void scan2_kernel(int* bsum, int* boff) {
    __shared__ int ws[4];
    int tid = threadIdx.x, lane = tid & 63, wid = tid >> 6;
    int v = (tid < 196) ? bsum[tid] : 0;
    int x = v;
    for (int o = 1; o < 64; o <<= 1) {
        int t = __shfl_up(x, o, 64);
        if (lane >= o) x += t;
    }
    if (lane == 63) ws[wid] = x;
    __syncthreads();
    if (tid == 0) {
        int acc = 0;
        for (int w = 0; w < 4; w++) { int t = ws[w]; ws[w] = acc; acc += t; }
    }
    __syncthreads();
    if (tid < 196) boff[tid] = x + ws[wid] - v;
}

__global__ void scan3_kernel(const int* __restrict__ deg, const int* __restrict__ boff,
                             int* off) {
    __shared__ int ws[4];
    int tid = threadIdx.x, lane = tid & 63, wid = tid >> 6;
    int i = blockIdx.x * 256 + tid;
    int v = (i < NN) ? deg[i] : 0;
    int x = v;
    for (int o = 1; o < 64; o <<= 1) {
        int t = __shfl_up(x, o, 64);
        if (lane >= o) x += t;
    }
    if (lane == 63) ws[wid] = x;
    __syncthreads();
    if (tid == 0) {
        int acc = 0;
        for (int w = 0; w < 4; w++) { int t = ws[w]; ws[w] = acc; acc += t; }
    }
    __syncthreads();
    int incl = x + ws[wid] + boff[blockIdx.x];
    if (i < NN) off[i + 1] = incl;
    if (i == 0) off[0] = 0;
}

// ---------------- rank via LDS + write packed edge record (no global atomics)
__global__ __launch_bounds__(256) void scatter_kernel(const int* __restrict__ ei,
                                                      const float* __restrict__ ea,
                                                      const unsigned short* __restrict__ base_g,
                                                      const int* __restrict__ soff,
                                                      uint4* __restrict__ erec) {
    __shared__ unsigned lc[NW];
    int b = blockIdx.x, tid = threadIdx.x;
    for (int w = tid; w < NW; w += 256) lc[w] = 0;
    __syncthreads();
    int e0 = b * EPB;
    const unsigned short* brow = base_g + (size_t)b * NN;
    for (int i = tid; i < EPB; i += 256) {
        int e = e0 + i;
        int d = ei[EE + e];
        int sh = (d & 3) * 8;
        unsigned old = atomicAdd(&lc[d >> 2], 1u << sh);
        int r = (int)((old >> sh) & 0xffu);
        int pos = soff[d] + (int)brow[d] + r;
        uint4 rec;
        rec.x = (unsigned)ei[e];
        rec.y = (unsigned)e;
        rec.z = __float_as_uint(ea[e]);
        rec.w = 0;
        erec[pos] = rec;
    }
}

// -------------------------------------- s[h] = dot(we[h*32: ], ae[h]) per layer
__global__ void preps_kernel(const float* we1, const float* ae1,
                             const float* we2, const float* ae2, float* s_out) {
    int tid = threadIdx.x;
    if (tid < 10) {
        const float* we = (tid < 5) ? we1 : we2;
        const float* ae = (tid < 5) ? ae1 : ae2;
        int h = tid % 5;
        float s = 0.f;
        for (int c = 0; c < 32; c++) s += we[h * 32 + c] * ae[h * 32 + c];
        s_out[tid] = s;
    }
}

#define ROWFMA(rr, av) \
    acc[rr][0] += (av) * b0; acc[rr][1] += (av) * b1; acc[rr][2] += (av) * b2; \
    acc[rr][3] += (av) * b3; acc[rr][4] += (av) * b4;

// ---------------- h = A @ W  (K = 128 or 160): 64 rows x 160 cols per block,
//                  8x5 register tile per thread; fused att-dot epilogue.
template <int K>
__global__ __launch_bounds__(256) void gemm_kernel(const float* __restrict__ A,
                                                   const float* __restrict__ W,
                                                   const float* __restrict__ a_s,
                                                   const float* __restrict__ a_d,
                                                   float* __restrict__ out,
                                                   float* __restrict__ al_s,
                                                   float* __restrict__ al_d) {
    __shared__ float As[32 * 64];    // [k][row]
    __shared__ float Bs[32 * 160];   // [k][c]
    __shared__ float hs[32 * 168];   // [row32][h*33 + c]  (head-padded)
    const int tid = threadIdx.x;
    const int base = blockIdx.x * 64;
    const int tc = tid & 31, tr = tid >> 5;       // col-thread, row-thread
    const int srow = tid >> 2, skq = tid & 3;     // staging map
    const bool rowok = (base + srow) < NN;
    const float* arow = A + (size_t)(base + srow) * K;

    float acc[8][5];
#pragma unroll
    for (int r = 0; r < 8; r++)
#pragma unroll
        for (int c = 0; c < 5; c++) acc[r][c] = 0.f;

    for (int k0 = 0; k0 < K; k0 += 32) {
        __syncthreads();
        // ---- stage A (transposed) : 64 rows x 32 k
        float4 av0 = make_float4(0.f, 0.f, 0.f, 0.f), av1 = av0;
        if (rowok) {
            av0 = *reinterpret_cast<const float4*>(arow + k0 + skq * 4);
            av1 = *reinterpret_cast<const float4*>(arow + k0 + 16 + skq * 4);
        }
        As[(skq * 4 + 0) * 64 + srow] = av0.x;
        As[(skq * 4 + 1) * 64 + srow] = av0.y;
        As[(skq * 4 + 2) * 64 + srow] = av0.z;
        As[(skq * 4 + 3) * 64 + srow] = av0.w;
        As[(skq * 4 + 16) * 64 + srow] = av1.x;
        As[(skq * 4 + 17) * 64 + srow] = av1.y;
        As[(skq * 4 + 18) * 64 + srow] = av1.z;
        As[(skq * 4 + 19) * 64 + srow] = av1.w;
        // ---- stage B : 32 k x 160 c  (1280 float4 / 256 threads)
#pragma unroll
        for (int i = 0; i < 5; i++) {
            int f = tid + 256 * i;
            int kk = f / 40, c4 = f - kk * 40;
            *reinterpret_cast<float4*>(&Bs[kk * 160 + c4 * 4]) =
                *reinterpret_cast<const float4*>(&W[(size_t)(k0 + kk) * HC + c4 * 4]);
        }
        __syncthreads();
#pragma unroll 8
        for (int k = 0; k < 32; k++) {
            const float4 a0 = *reinterpret_cast<const float4*>(&As[k * 64 + tr * 8]);
            const float4 a1 = *reinterpret_cast<const float4*>(&As[k * 64 + tr * 8 + 4]);
            const float b0 = Bs[k * 160 + tc];
            const float b1 = Bs[k * 160 + tc + 32];
            const float b2 = Bs[k * 160 + tc + 64];
            const float b3 = Bs[k * 160 + tc + 96];
            const float b4 = Bs[k * 160 + tc + 128];
            ROWFMA(0, a0.x) ROWFMA(1, a0.y) ROWFMA(2, a0.z) ROWFMA(3, a0.w)
            ROWFMA(4, a1.x) ROWFMA(5, a1.y) ROWFMA(6, a1.z) ROWFMA(7, a1.w)
        }
    }
    // ---- store h
#pragma unroll
    for (int r = 0; r < 8; r++) {
        int grow = base + tr * 8 + r;
        if (grow < NN) {
            float* op = out + (size_t)grow * HC + tc;
            op[0] = acc[r][0]; op[32] = acc[r][1]; op[64] = acc[r][2];
            op[96] = acc[r][3]; op[128] = acc[r][4];
        }
    }
    // ---- att-dot epilogue: two halves of 32 rows via hs
    for (int half = 0; half < 2; half++) {
        __syncthreads();
        if ((tr >> 2) == half) {
            int r32 = (tr & 3) * 8;
#pragma unroll
            for (int r = 0; r < 8; r++)
#pragma unroll
                for (int ci = 0; ci < 5; ci++)
                    hs[(r32 + r) * 168 + ci * 33 + tc] = acc[r][ci];
        }
        __syncthreads();
        for (int t = tid; t < 320; t += 256) {
            int row32 = t / 10;
            int rem = t - row32 * 10;
            int h = rem >> 1, sd = rem & 1;
            int grow = base + half * 32 + row32;
            if (grow < NN) {
                const float* av = (sd ? a_d : a_s) + h * 32;
                const float* hp = &hs[row32 * 168 + h * 33];
                float s = 0.f;
#pragma unroll
                for (int c = 0; c < 32; c++) s += hp[c] * av[c];
                if (sd) al_d[(size_t)grow * NH + h] = s;
                else    al_s[(size_t)grow * ALS8 + h] = s;
            }
        }
    }
}

// ------------- per-node (one WAVE per node, 4 nodes per block): segment softmax
//               + weighted gather + bias/lrelu/LN.  Exactly ONE __syncthreads on
//               both paths (waves may take different paths; barrier counts match).
__global__ __launch_bounds__(256, 8) void aggregate_kernel(
    const int* __restrict__ soff, const uint4* __restrict__ erec,
    const float* __restrict__ hfeat, const float* __restrict__ als,
    const float* __restrict__ al_d, const float* __restrict__ s_e,
    const float* __restrict__ bias, const float* __restrict__ g_ln,
    const float* __restrict__ b_ln,
    float* __restrict__ alpha_out, float* __restrict__ x_out) {
    const int wave = threadIdx.x >> 6;
    const int lane = threadIdx.x & 63;
    const int n = blockIdx.x * 4 + wave;
    __shared__ float w_sh_all[4][CH * NH];
    __shared__ int isrc_all[4][CH];
    float* w_sh = w_sh_all[wave];
    int* isrc_sh = isrc_all[wave];

    const int s0 = soff[n];
    const int deg = soff[n + 1] - s0;
    const int items = deg + 1;

    float adr[NH], ser[NH];
#pragma unroll
    for (int h = 0; h < NH; h++) { adr[h] = al_d[n * NH + h]; ser[h] = s_e[h]; }

    const int c0 = 4 * lane;      // lanes 0..39 own channels c0..c0+3 (float4)
    const int hd = lane >> 3;     // head for those channels (valid for lane<40)
    float4 acc = make_float4(0.f, 0.f, 0.f, 0.f);

    if (items <= CH) {
        // ---- pass A: logits into registers (2 tiles x 5 heads), per-head max, ea sum
        float rw[2][NH];
        float lm[NH];
#pragma unroll
        for (int h = 0; h < NH; h++) lm[h] = -3.0e38f;
        float eas = 0.f;
        int myy[2];
#pragma unroll
        for (int t = 0; t < 2; t++) {
            int i = lane + 64 * t;
            if (i < deg) {
                uint4 rec = erec[s0 + i];
                int src = (int)rec.x;
                float eav = __uint_as_float(rec.z);
                isrc_sh[i] = src;
                myy[t] = (int)rec.y;
                eas += eav;
                const float* ap = als + (size_t)src * ALS8;
                float4 a4 = *reinterpret_cast<const float4*>(ap);
                float a5 = ap[4];
                float asv[5] = {a4.x, a4.y, a4.z, a4.w, a5};
#pragma unroll
                for (int h = 0; h < NH; h++) {
                    float r = lrelu(asv[h] + adr[h] + eav * ser[h], 0.2f);
                    rw[t][h] = r;
                    lm[h] = fmaxf(lm[h], r);
                }
            }
        }
#pragma unroll
        for (int o = 1; o < 64; o <<= 1) {
#pragma unroll
            for (int h = 0; h < NH; h++) lm[h] = fmaxf(lm[h], __shfl_xor(lm[h], o, 64));
            eas += __shfl_xor(eas, o, 64);
        }
        float emean = eas / fmaxf((float)deg, 1.f);
        float m[NH], rs[NH];
        {
            const float* ap = als + (size_t)n * ALS8;
            float4 a4 = *reinterpret_cast<const float4*>(ap);
            float a5 = ap[4];
            float asv[5] = {a4.x, a4.y, a4.z, a4.w, a5};
#pragma unroll
            for (int h = 0; h < NH; h++) {
                rs[h] = lrelu(asv[h] + adr[h] + emean * ser[h], 0.2f);
                m[h] = fmaxf(lm[h], rs[h]);
            }
        }
        // ---- pass B: exp in registers + sum
        float ls[NH] = {0.f, 0.f, 0.f, 0.f, 0.f};
#pragma unroll
        for (int t = 0; t < 2; t++) {
            int i = lane + 64 * t;
            if (i < deg) {
#pragma unroll
                for (int h = 0; h < NH; h++) {
                    float w = expf(rw[t][h] - m[h]);
                    rw[t][h] = w;
                    ls[h] += w;
                }
            } else if (i == deg) {          // self-loop owner lane
                isrc_sh[i] = n;
#pragma unroll
                for (int h = 0; h < NH; h++) {
                    float w = expf(rs[h] - m[h]);
                    rw[t][h] = w;
                    ls[h] += w;
                }
            }
        }
#pragma unroll
        for (int o = 1; o < 64; o <<= 1) {
#pragma unroll
            for (int h = 0; h < NH; h++) ls[h] += __shfl_xor(ls[h], o, 64);
        }
        float dinv[NH];
#pragma unroll
        for (int h = 0; h < NH; h++) dinv[h] = 1.f / ls[h];
        // ---- normalize: final weights -> LDS + alpha writeback
#pragma unroll
        for (int t = 0; t < 2; t++) {
            int i = lane + 64 * t;
            if (i < items) {
                int opos = (i < deg) ? myy[t] : (EE + n);
#pragma unroll
                for (int h = 0; h < NH; h++) {
                    float w = rw[t][h] * dinv[h];
                    w_sh[i * NH + h] = w;
                    alpha_out[(size_t)opos * NH + h] = w;
                }
            }
        }
        __syncthreads();                                   // [barrier #1 of 1]
        // ---- pass C: 4-deep pipelined float4 gather (lanes 0..39)
        if (lane < 40) {
            for (int i0 = 0; i0 < items; i0 += 4) {
                float wv[4];
                const float4* hp[4];
#pragma unroll
                for (int j = 0; j < 4; j++) {
                    int i = i0 + j;
                    bool ok = i < items;
                    int ii = ok ? i : 0;
                    wv[j] = ok ? w_sh[ii * NH + hd] : 0.f;
                    hp[j] = reinterpret_cast<const float4*>(
                        &hfeat[(size_t)isrc_sh[ii] * HC + c0]);
                }
                float4 h0 = *hp[0], h1 = *hp[1], h2 = *hp[2], h3 = *hp[3];
                acc.x += wv[0] * h0.x + wv[1] * h1.x + wv[2] * h2.x + wv[3] * h3.x;
                acc.y += wv[0] * h0.y + wv[1] * h1.y + wv[2] * h2.y + wv[3] * h3.y;
                acc.z += wv[0] * h0.z + wv[1] * h1.z + wv[2] * h2.z + wv[3] * h3.z;
                acc.w += wv[0] * h0.w + wv[1] * h1.w + wv[2] * h2.w + wv[3] * h3.w;
            }
        }
    } else {
        // ---- slow path (deg >= CH): streaming recompute, no LDS
        float lm[NH];
#pragma unroll
        for (int h = 0; h < NH; h++) lm[h] = -3.0e38f;
        float eas = 0.f;
        for (int i = lane; i < deg; i += 64) {
            uint4 rec = erec[s0 + i];
            int src = (int)rec.x;
            float eav = __uint_as_float(rec.z);
            eas += eav;
            const float* ap = als + (size_t)src * ALS8;
            float4 a4 = *reinterpret_cast<const float4*>(ap);
            float a5 = ap[4];
            float asv[5] = {a4.x, a4.y, a4.z, a4.w, a5};
#pragma unroll
            for (int h = 0; h < NH; h++) {
                float r = lrelu(asv[h] + adr[h] + eav * ser[h], 0.2f);
                lm[h] = fmaxf(lm[h], r);
            }
        }
#pragma unroll
        for (int o = 1; o < 64; o <<= 1) {
#pragma unroll
            for (int h = 0; h < NH; h++) lm[h] = fmaxf(lm[h], __shfl_xor(lm[h], o, 64));
            eas += __shfl_xor(eas, o, 64);
        }
        float emean = eas / fmaxf((float)deg, 1.f);
        float m[NH], rs[NH];
        {
            const float* ap = als + (size_t)n * ALS8;
#pragma unroll
            for (int h = 0; h < NH; h++) {
                rs[h] = lrelu(ap[h] + adr[h] + emean * ser[h], 0.2f);
                m[h] = fmaxf(lm[h], rs[h]);
            }
        }
        float ls[NH] = {0.f, 0.f, 0.f, 0.f, 0.f};
        for (int i = lane; i < items; i += 64) {
            int src; float eav;
            if (i < deg) { uint4 rec = erec[s0 + i]; src = (int)rec.x; eav = __uint_as_float(rec.z); }
            else         { src = n; eav = emean; }
            const float* ap = als + (size_t)src * ALS8;
#pragma unroll
            for (int h = 0; h < NH; h++) {
                float r = lrelu(ap[h] + adr[h] + eav * ser[h], 0.2f);
                ls[h] += expf(r - m[h]);
            }
        }
#pragma unroll
        for (int o = 1; o < 64; o <<= 1) {
#pragma unroll
            for (int h = 0; h < NH; h++) ls[h] += __shfl_xor(ls[h], o, 64);
        }
        float dinv[NH];
#pragma unroll
        for (int h = 0; h < NH; h++) dinv[h] = 1.f / ls[h];
        __syncthreads();                                   // [barrier #1 of 1]
        for (int i = lane; i < items; i += 64) {
            int src; float eav; int opos;
            if (i < deg) { uint4 rec = erec[s0 + i]; src = (int)rec.x; eav = __uint_as_float(rec.z); opos = (int)rec.y; }
            else         { src = n; eav = emean; opos = EE + n; }
            const float* ap = als + (size_t)src * ALS8;
#pragma unroll
            for (int h = 0; h < NH; h++) {
                float r = lrelu(ap[h] + adr[h] + eav * ser[h], 0.2f);
                alpha_out[(size_t)opos * NH + h] = expf(r - m[h]) * dinv[h];
            }
        }
        if (lane < 40) {
            for (int i = 0; i < items; i++) {
                int src; float eav;
                if (i < deg) { uint4 rec = erec[s0 + i]; src = (int)rec.x; eav = __uint_as_float(rec.z); }
                else         { src = n; eav = emean; }
                float r = lrelu(als[(size_t)src * ALS8 + hd] + adr[hd] + eav * ser[hd], 0.2f);
                float w = expf(r - m[hd]) * dinv[hd];
                const float4 hv = *reinterpret_cast<const float4*>(
                    &hfeat[(size_t)src * HC + c0]);
                acc.x += w * hv.x; acc.y += w * hv.y;
                acc.z += w * hv.z; acc.w += w * hv.w;
            }
        }
    }

    // ---- bias + lrelu + fused LayerNorm across 160 channels (wave butterfly)
    float4 v = make_float4(0.f, 0.f, 0.f, 0.f);
    float p1 = 0.f, p2 = 0.f;
    if (lane < 40) {
        const float4 b4 = *reinterpret_cast<const float4*>(&bias[c0]);
        v.x = lrelu(acc.x + b4.x, 0.01f);
        v.y = lrelu(acc.y + b4.y, 0.01f);
        v.z = lrelu(acc.z + b4.z, 0.01f);
        v.w = lrelu(acc.w + b4.w, 0.01f);
        p1 = v.x + v.y + v.z + v.w;
        p2 = v.x * v.x + v.y * v.y + v.z * v.z + v.w * v.w;
    }
#pragma unroll
    for (int o = 1; o < 64; o <<= 1) {
        p1 += __shfl_xor(p1, o, 64);
        p2 += __shfl_xor(p2, o, 64);
    }
    float mean = p1 * (1.f / (float)HC);
    float var = p2 * (1.f / (float)HC) - mean * mean;
    float rstd = rsqrtf(var + 1e-5f);
    if (lane < 40) {
        const float4 g4 = *reinterpret_cast<const float4*>(&g_ln[c0]);
        const float4 bb = *reinterpret_cast<const float4*>(&b_ln[c0]);
        float4 o4;
        o4.x = (v.x - mean) * rstd * g4.x + bb.x;
        o4.y = (v.y - mean) * rstd * g4.y + bb.y;
        o4.z = (v.z - mean) * rstd * g4.z + bb.z;
        o4.w = (v.w - mean) * rstd * g4.w + bb.w;
        *reinterpret_cast<float4*>(&x_out[(size_t)n * HC + c0]) = o4;
    }
}

// -------- x3 = lrelu(x2 @ mw + mb); 64x160 register-blocked; fused pooled sums
__global__ __launch_bounds__(256) void gemm3_kernel(const float* __restrict__ A,
                                                    const float* __restrict__ W,
                                                    const float* __restrict__ bias,
                                                    const int* __restrict__ batch,
                                                    float* __restrict__ x3,
                                                    float* __restrict__ psum) {
    __shared__ float As[32 * 64];
    __shared__ float Bs[32 * 160];
    __shared__ int bt[64];
    const int tid = threadIdx.x;
    const int base = blockIdx.x * 64;
    const int tc = tid & 31, tr = tid >> 5;
    const int srow = tid >> 2, skq = tid & 3;
    const bool rowok = (base + srow) < NN;
    const float* arow = A + (size_t)(base + srow) * HC;

    float acc[8][5];
#pragma unroll
    for (int r = 0; r < 8; r++)
#pragma unroll
        for (int c = 0; c < 5; c++) acc[r][c] = 0.f;

    for (int k0 = 0; k0 < HC; k0 += 32) {
        __syncthreads();
        float4 av0 = make_float4(0.f, 0.f, 0.f, 0.f), av1 = av0;
        if (rowok) {
            av0 = *reinterpret_cast<const float4*>(arow + k0 + skq * 4);
            av1 = *reinterpret_cast<const float4*>(arow + k0 + 16 + skq * 4);
        }
        As[(skq * 4 + 0) * 64 + srow] = av0.x;
        As[(skq * 4 + 1) * 64 + srow] = av0.y;
        As[(skq * 4 + 2) * 64 + srow] = av0.z;
        As[(skq * 4 + 3) * 64 + srow] = av0.w;
        As[(skq * 4 + 16) * 64 + srow] = av1.x;
        As[(skq * 4 + 17) * 64 + srow] = av1.y;
        As[(skq * 4 + 18) * 64 + srow] = av1.z;
        As[(skq * 4 + 19) * 64 + srow] = av1.w;
#pragma unroll
        for (int i = 0; i < 5; i++) {
            int f = tid + 256 * i;
            int kk = f / 40, c4 = f - kk * 40;
            *reinterpret_cast<float4*>(&Bs[kk * 160 + c4 * 4]) =
                *reinterpret_cast<const float4*>(&W[(size_t)(k0 + kk) * HC + c4 * 4]);
        }
        if (k0 == 0 && tid < 64)
            bt[tid] = batch[(base + tid < NN) ? (base + tid) : (NN - 1)];
        __syncthreads();
#pragma unroll 8
        for (int k = 0; k < 32; k++) {
            const float4 a0 = *reinterpret_cast<const float4*>(&As[k * 64 + tr * 8]);
            const float4 a1 = *reinterpret_cast<const float4*>(&As[k * 64 + tr * 8 + 4]);
            const float b0 = Bs[k * 160 + tc];
            const float b1 = Bs[k * 160 + tc + 32];
            const float b2 = Bs[k * 160 + tc + 64];
            const float b3 = Bs[k * 160 + tc + 96];
            const float b4 = Bs[k * 160 + tc + 128];
            ROWFMA(0, a0.x) ROWFMA(1, a0.y) ROWFMA(2, a0.z) ROWFMA(3, a0.w)
            ROWFMA(4, a1.x) ROWFMA(5, a1.y) ROWFMA(6, a1.z) ROWFMA(7, a1.w)
        }
    }
    float bj[5];
#pragma unroll
    for (int ci = 0; ci < 5; ci++) bj[ci] = bias[tc + 32 * ci];
    float run[5] = {0.f, 0.f, 0.f, 0.f, 0.f};
    int g = bt[tr * 8];
#pragma unroll
    for (int r = 0; r < 8; r++) {
        int grow = base + tr * 8 + r;
        bool ok = grow < NN;
        float vv[5];
#pragma unroll
        for (int ci = 0; ci < 5; ci++) vv[ci] = lrelu(acc[r][ci] + bj[ci], 0.01f);
        if (ok) {
            float* op = x3 + (size_t)grow * HC + tc;
            op[0] = vv[0]; op[32] = vv[1]; op[64] = vv[2]; op[96] = vv[3]; op[128] = vv[4];
        }
        int gb = bt[tr * 8 + r];
        if (gb != g) {
#pragma unroll
            for (int ci = 0; ci < 5; ci++) {
                atomicAdd(&psum[g * HC + tc + 32 * ci], run[ci]);
                run[ci] = 0.f;
            }
            g = gb;
        }
        if (ok) {
#pragma unroll
            for (int ci = 0; ci < 5; ci++) run[ci] += vv[ci];
        }
    }
#pragma unroll
    for (int ci = 0; ci < 5; ci++) atomicAdd(&psum[g * HC + tc + 32 * ci], run[ci]);
}

__global__ void pooldiv_kernel(const float* __restrict__ psum, const int* __restrict__ gcnt,
                               float* pooled_out) {
    int i = blockIdx.x * 256 + threadIdx.x;
    if (i < NG * HC) pooled_out[i] = psum[i] / fmaxf((float)gcnt[i / HC], 1.f);
}

// ---------------------------------------------------------------------- launch
extern "C" void kernel_launch(void* const* d_in, const int* in_sizes, int n_in,
                              void* d_out, int out_size, void* d_ws, size_t ws_size,
                              hipStream_t stream) {
    const float* x    = (const float*)d_in[0];
    const int*   ei   = (const int*)d_in[1];
    const float* ea   = (const float*)d_in[2];
    const int*   batch= (const int*)d_in[3];
    const float* w1   = (const float*)d_in[4];
    const float* we1  = (const float*)d_in[5];
    const float* as1  = (const float*)d_in[6];
    const float* ad1  = (const float*)d_in[7];
    const float* ae1  = (const float*)d_in[8];
    const float* b1   = (const float*)d_in[9];
    const float* w2   = (const float*)d_in[10];
    const float* we2  = (const float*)d_in[11];
    const float* as2  = (const float*)d_in[12];
    const float* ad2  = (const float*)d_in[13];
    const float* ae2  = (const float*)d_in[14];
    const float* b2   = (const float*)d_in[15];
    const float* ln1g = (const float*)d_in[16];
    const float* ln1b = (const float*)d_in[17];
    const float* ln2g = (const float*)d_in[18];
    const float* ln2b = (const float*)d_in[19];
    const float* mw   = (const float*)d_in[20];
    const float* mb   = (const float*)d_in[21];

    float* out = (float*)d_out;
    float* x12 = out;                                 // x1/x2 scratch in x3 region
    float* pooled_out = out + (size_t)NN * HC;
    float* a1 = pooled_out + NG * HC;
    float* a2 = a1 + (size_t)(EE + NN) * NH;

    char* wp = (char*)d_ws;
    auto alloc = [&](size_t bytes) {
        void* p = (void*)wp;
        wp += (bytes + 255) & ~(size_t)255;
        return p;
    };
    float* hbuf  = (float*)alloc((size_t)NN * HC * 4);   // 32 MB
    // hist_g/base_g overlay hbuf (dead before gemm1 writes hbuf)
    unsigned*       hist_g = (unsigned*)hbuf;                       // 8 MB
    unsigned short* base_g = (unsigned short*)((char*)hbuf + 8 * 1024 * 1024); // 16 MB
    uint4* erec  = (uint4*)alloc((size_t)EE * 16);       // 12.8 MB
    float* als   = (float*)alloc((size_t)NN * ALS8 * 4); // padded al_s
    float* ald   = (float*)alloc((size_t)NN * NH * 4);
    int*   deg   = (int*)alloc((size_t)NN * 4);
    int*   soff  = (int*)alloc((size_t)(NN + 1) * 4);
    float* sbuf  = (float*)alloc(64);
    float* psum  = (float*)alloc((size_t)NG * HC * 4);
    int*   gcnt  = (int*)alloc((size_t)NG * 4);
    int*   bsum  = (int*)alloc(256 * 4);
    int*   boff  = (int*)alloc(256 * 4);

    prep_kernel<<<40, 256, 0, stream>>>(batch, psum, gcnt);
    hist_kernel<<<NB, 256, 0, stream>>>(ei, hist_g);
    sscan_kernel<<<49, 256, 0, stream>>>(hist_g, base_g, deg);
    scan1_kernel<<<196, 256, 0, stream>>>(deg, bsum);
    scan2_kernel<<<1, 256, 0, stream>>>(bsum, boff);
    scan3_kernel<<<196, 256, 0, stream>>>(deg, boff, soff);
    scatter_kernel<<<NB, 256, 0, stream>>>(ei, ea, base_g, soff, erec);
    preps_kernel<<<1, 64, 0, stream>>>(we1, ae1, we2, ae2, sbuf);

    gemm_kernel<128><<<782, 256, 0, stream>>>(x, w1, as1, ad1, hbuf, als, ald);
    aggregate_kernel<<<12500, 256, 0, stream>>>(soff, erec, hbuf, als, ald,
                                                sbuf, b1, ln1g, ln1b, a1, x12);

    gemm_kernel<160><<<782, 256, 0, stream>>>(x12, w2, as2, ad2, hbuf, als, ald);
    aggregate_kernel<<<12500, 256, 0, stream>>>(soff, erec, hbuf, als, ald,
                                                sbuf + 5, b2, ln2g, ln2b, a2, x12);

    gemm3_kernel<<<782, 256, 0, stream>>>(x12, mw, mb, batch, out, psum);
    pooldiv_kernel<<<40, 256, 0, stream>>>(psum, gcnt, pooled_out);
}

// Round 3
// 519.387 us; speedup vs baseline: 1.1130x; 1.1130x over previous
//
#include <hip/hip_runtime.h>
#include <hip/hip_fp16.h>
#include <math.h>

#define NN 50000
#define EE 800000
#define FIN 128
#define NH 5
#define HC 160
#define NG 64
#define CH 128        // fast-path max items per node (deg <= 127)
#define NB 160        // sort blocks
#define EPB 5000      // edges per sort block (NB*EPB == EE)
#define NW 12500      // packed histogram words (4 byte-bins per word)
#define ALS8 8        // padded stride for al_s (float4 + float loads)

__device__ __forceinline__ float lrelu(float x, float s) { return x >= 0.f ? x : s * x; }

// unpack 4 consecutive fp16 (8B) to float4
__device__ __forceinline__ float4 h8_to_f4(uint2 u) {
    __half2 a = *reinterpret_cast<__half2*>(&u.x);
    __half2 b = *reinterpret_cast<__half2*>(&u.y);
    float2 fa = __half22float2(a), fb = __half22float2(b);
    return make_float4(fa.x, fa.y, fb.x, fb.y);
}

// ---------------- psum zero + per-graph node counts via binary search (batch sorted)
__global__ void prep_kernel(const int* __restrict__ batch, float* psum, int* gcnt) {
    int i = blockIdx.x * 256 + threadIdx.x;
    if (i < NG * HC) psum[i] = 0.f;
    if (i < NG) {
        int lo = 0, hi = NN;
        while (lo < hi) { int m = (lo + hi) >> 1; if (batch[m] < i) lo = m + 1; else hi = m; }
        int s = lo;
        lo = 0; hi = NN;
        int g1 = i + 1;
        while (lo < hi) { int m = (lo + hi) >> 1; if (batch[m] < g1) lo = m + 1; else hi = m; }
        gcnt[i] = lo - s;
    }
}

// ---------------- per-block LDS histogram of dst (byte-packed, no global atomics)
__global__ __launch_bounds__(256) void hist_kernel(const int* __restrict__ ei,
                                                   unsigned* __restrict__ hist_g) {
    __shared__ unsigned lh[NW];
    int b = blockIdx.x, tid = threadIdx.x;
    for (int w = tid; w < NW; w += 256) lh[w] = 0;
    __syncthreads();
    const int* dstp = ei + EE + b * EPB;
    for (int i = tid; i < EPB; i += 256) {
        int d = dstp[i];
        atomicAdd(&lh[d >> 2], 1u << ((d & 3) * 8));
    }
    __syncthreads();
    unsigned* outp = hist_g + (size_t)b * NW;
    for (int w = tid; w < NW; w += 256) outp[w] = lh[w];
}

// ---------------- column scan over blocks: per-(block,bin) base + total deg
__global__ void sscan_kernel(const unsigned* __restrict__ hist_g,
                             unsigned short* __restrict__ base_g, int* __restrict__ deg) {
    int w = blockIdx.x * 256 + threadIdx.x;
    if (w >= NW) return;
    unsigned r0 = 0, r1 = 0, r2 = 0, r3 = 0;
    for (int b = 0; b < NB; b++) {
        unsigned x = hist_g[(size_t)b * NW + w];
        uint2 st;
        st.x = r0 | (r1 << 16);
        st.y = r2 | (r3 << 16);
        *reinterpret_cast<uint2*>(&base_g[(size_t)b * NN + 4 * w]) = st;
        r0 += x & 0xffu; r1 += (x >> 8) & 0xffu; r2 += (x >> 16) & 0xffu; r3 += (x >> 24) & 0xffu;
    }
    uint4 dv; dv.x = r0; dv.y = r1; dv.z = r2; dv.w = r3;
    *reinterpret_cast<uint4*>(&deg[4 * w]) = dv;
}

// ------------------------------------------------------- 3-phase parallel scan
__global__ void scan1_kernel(const int* __restrict__ deg, int* bsum) {
    __shared__ int ws[4];
    int tid = threadIdx.x, lane = tid & 63, wid = tid >> 6;
    int i = blockIdx.x * 256 + tid;
    int v = (i < NN) ? deg[i] : 0;
    for (int o = 32; o >= 1; o >>= 1) v += __shfl_down(v, o, 64);
    if (lane == 0) ws[wid] = v;
    __syncthreads();
    if (tid == 0) bsum[blockIdx.x] = ws[0] + ws[1] + ws[2] + ws[3];
}

__global__ void scan2_kernel(int* bsum, int* boff) {
    __shared__ int ws[4];
    int tid = threadIdx.x, lane = tid & 63, wid = tid >> 6;
    int v = (tid < 196) ? bsum[tid] : 0;
    int x = v;
    for (int o = 1; o < 64; o <<= 1) {
        int t = __shfl_up(x, o, 64);
        if (lane >= o) x += t;
    }
    if (lane == 63) ws[wid] = x;
    __syncthreads();
    if (tid == 0) {
        int acc = 0;
        for (int w = 0; w < 4; w++) { int t = ws[w]; ws[w] = acc; acc += t; }
    }
    __syncthreads();
    if (tid < 196) boff[tid] = x + ws[wid] - v;
}

__global__ void scan3_kernel(const int* __restrict__ deg, const int* __restrict__ boff,
                             int* off) {
    __shared__ int ws[4];
    int tid = threadIdx.x, lane = tid & 63, wid = tid >> 6;
    int i = blockIdx.x * 256 + tid;
    int v = (i < NN) ? deg[i] : 0;
    int x = v;
    for (int o = 1; o < 64; o <<= 1) {
        int t = __shfl_up(x, o, 64);
        if (lane >= o) x += t;
    }
    if (lane == 63) ws[wid] = x;
    __syncthreads();
    if (tid == 0) {
        int acc = 0;
        for (int w = 0; w < 4; w++) { int t = ws[w]; ws[w] = acc; acc += t; }
    }
    __syncthreads();
    int incl = x + ws[wid] + boff[blockIdx.x];
    if (i < NN) off[i + 1] = incl;
    if (i == 0) off[0] = 0;
}

// ---------------- rank via LDS + write packed edge record (no global atomics)
__global__ __launch_bounds__(256) void scatter_kernel(const int* __restrict__ ei,
                                                      const float* __restrict__ ea,
                                                      const unsigned short* __restrict__ base_g,
                                                      const int* __restrict__ soff,
                                                      uint4* __restrict__ erec) {
    __shared__ unsigned lc[NW];
    int b = blockIdx.x, tid = threadIdx.x;
    for (int w = tid; w < NW; w += 256) lc[w] = 0;
    __syncthreads();
    int e0 = b * EPB;
    const unsigned short* brow = base_g + (size_t)b * NN;
    for (int i = tid; i < EPB; i += 256) {
        int e = e0 + i;
        int d = ei[EE + e];
        int sh = (d & 3) * 8;
        unsigned old = atomicAdd(&lc[d >> 2], 1u << sh);
        int r = (int)((old >> sh) & 0xffu);
        int pos = soff[d] + (int)brow[d] + r;
        uint4 rec;
        rec.x = (unsigned)ei[e];
        rec.y = (unsigned)e;
        rec.z = __float_as_uint(ea[e]);
        rec.w = 0;
        erec[pos] = rec;
    }
}

// -------------------------------------- s[h] = dot(we[h*32: ], ae[h]) per layer
__global__ void preps_kernel(const float* we1, const float* ae1,
                             const float* we2, const float* ae2, float* s_out) {
    int tid = threadIdx.x;
    if (tid < 10) {
        const float* we = (tid < 5) ? we1 : we2;
        const float* ae = (tid < 5) ? ae1 : ae2;
        int h = tid % 5;
        float s = 0.f;
        for (int c = 0; c < 32; c++) s += we[h * 32 + c] * ae[h * 32 + c];
        s_out[tid] = s;
    }
}

#define ROWFMA(rr, av) \
    acc[rr][0] += (av) * b0; acc[rr][1] += (av) * b1; acc[rr][2] += (av) * b2; \
    acc[rr][3] += (av) * b3; acc[rr][4] += (av) * b4;

// ---------------- h = A @ W  (K = 128 or 160): 64 rows x 160 cols per block,
//                  8x5 register tile per thread; fused att-dot epilogue.
//                  h is stored fp16 (gather traffic); att dots from fp32 accs.
template <int K>
__global__ __launch_bounds__(256) void gemm_kernel(const float* __restrict__ A,
                                                   const float* __restrict__ W,
                                                   const float* __restrict__ a_s,
                                                   const float* __restrict__ a_d,
                                                   __half* __restrict__ out,
                                                   float* __restrict__ al_s,
                                                   float* __restrict__ al_d) {
    __shared__ float As[32 * 64];    // [k][row]
    __shared__ float Bs[32 * 160];   // [k][c]
    __shared__ float hs[32 * 168];   // [row32][h*33 + c]  (head-padded)
    const int tid = threadIdx.x;
    const int base = blockIdx.x * 64;
    const int tc = tid & 31, tr = tid >> 5;       // col-thread, row-thread
    const int srow = tid >> 2, skq = tid & 3;     // staging map
    const bool rowok = (base + srow) < NN;
    const float* arow = A + (size_t)(base + srow) * K;

    float acc[8][5];
#pragma unroll
    for (int r = 0; r < 8; r++)
#pragma unroll
        for (int c = 0; c < 5; c++) acc[r][c] = 0.f;

    for (int k0 = 0; k0 < K; k0 += 32) {
        __syncthreads();
        // ---- stage A (transposed) : 64 rows x 32 k
        float4 av0 = make_float4(0.f, 0.f, 0.f, 0.f), av1 = av0;
        if (rowok) {
            av0 = *reinterpret_cast<const float4*>(arow + k0 + skq * 4);
            av1 = *reinterpret_cast<const float4*>(arow + k0 + 16 + skq * 4);
        }
        As[(skq * 4 + 0) * 64 + srow] = av0.x;
        As[(skq * 4 + 1) * 64 + srow] = av0.y;
        As[(skq * 4 + 2) * 64 + srow] = av0.z;
        As[(skq * 4 + 3) * 64 + srow] = av0.w;
        As[(skq * 4 + 16) * 64 + srow] = av1.x;
        As[(skq * 4 + 17) * 64 + srow] = av1.y;
        As[(skq * 4 + 18) * 64 + srow] = av1.z;
        As[(skq * 4 + 19) * 64 + srow] = av1.w;
        // ---- stage B : 32 k x 160 c  (1280 float4 / 256 threads)
#pragma unroll
        for (int i = 0; i < 5; i++) {
            int f = tid + 256 * i;
            int kk = f / 40, c4 = f - kk * 40;
            *reinterpret_cast<float4*>(&Bs[kk * 160 + c4 * 4]) =
                *reinterpret_cast<const float4*>(&W[(size_t)(k0 + kk) * HC + c4 * 4]);
        }
        __syncthreads();
#pragma unroll 8
        for (int k = 0; k < 32; k++) {
            const float4 a0 = *reinterpret_cast<const float4*>(&As[k * 64 + tr * 8]);
            const float4 a1 = *reinterpret_cast<const float4*>(&As[k * 64 + tr * 8 + 4]);
            const float b0 = Bs[k * 160 + tc];
            const float b1 = Bs[k * 160 + tc + 32];
            const float b2 = Bs[k * 160 + tc + 64];
            const float b3 = Bs[k * 160 + tc + 96];
            const float b4 = Bs[k * 160 + tc + 128];
            ROWFMA(0, a0.x) ROWFMA(1, a0.y) ROWFMA(2, a0.z) ROWFMA(3, a0.w)
            ROWFMA(4, a1.x) ROWFMA(5, a1.y) ROWFMA(6, a1.z) ROWFMA(7, a1.w)
        }
    }
    // ---- store h (fp16)
#pragma unroll
    for (int r = 0; r < 8; r++) {
        int grow = base + tr * 8 + r;
        if (grow < NN) {
            __half* op = out + (size_t)grow * HC + tc;
            op[0]   = __float2half(acc[r][0]);
            op[32]  = __float2half(acc[r][1]);
            op[64]  = __float2half(acc[r][2]);
            op[96]  = __float2half(acc[r][3]);
            op[128] = __float2half(acc[r][4]);
        }
    }
    // ---- att-dot epilogue: two halves of 32 rows via hs (fp32 accs)
    for (int half = 0; half < 2; half++) {
        __syncthreads();
        if ((tr >> 2) == half) {
            int r32 = (tr & 3) * 8;
#pragma unroll
            for (int r = 0; r < 8; r++)
#pragma unroll
                for (int ci = 0; ci < 5; ci++)
                    hs[(r32 + r) * 168 + ci * 33 + tc] = acc[r][ci];
        }
        __syncthreads();
        for (int t = tid; t < 320; t += 256) {
            int row32 = t / 10;
            int rem = t - row32 * 10;
            int h = rem >> 1, sd = rem & 1;
            int grow = base + half * 32 + row32;
            if (grow < NN) {
                const float* av = (sd ? a_d : a_s) + h * 32;
                const float* hp = &hs[row32 * 168 + h * 33];
                float s = 0.f;
#pragma unroll
                for (int c = 0; c < 32; c++) s += hp[c] * av[c];
                if (sd) al_d[(size_t)grow * NH + h] = s;
                else    al_s[(size_t)grow * ALS8 + h] = s;
            }
        }
    }
}

// ------------- per-node (one WAVE per node, 4 nodes per block): segment softmax
//               + weighted gather (fp16 h) + bias/lrelu/LN.  Exactly ONE
//               __syncthreads on both paths.
__global__ __launch_bounds__(256, 8) void aggregate_kernel(
    const int* __restrict__ soff, const uint4* __restrict__ erec,
    const __half* __restrict__ hfeat, const float* __restrict__ als,
    const float* __restrict__ al_d, const float* __restrict__ s_e,
    const float* __restrict__ bias, const float* __restrict__ g_ln,
    const float* __restrict__ b_ln,
    float* __restrict__ alpha_out, float* __restrict__ x_out) {
    const int wave = threadIdx.x >> 6;
    const int lane = threadIdx.x & 63;
    const int n = blockIdx.x * 4 + wave;
    __shared__ float w_sh_all[4][CH * NH];
    __shared__ int isrc_all[4][CH];
    float* w_sh = w_sh_all[wave];
    int* isrc_sh = isrc_all[wave];

    const int s0 = soff[n];
    const int deg = soff[n + 1] - s0;
    const int items = deg + 1;

    float adr[NH], ser[NH];
#pragma unroll
    for (int h = 0; h < NH; h++) { adr[h] = al_d[n * NH + h]; ser[h] = s_e[h]; }

    const int c0 = 4 * lane;      // lanes 0..39 own channels c0..c0+3
    const int hd = lane >> 3;     // head for those channels (valid for lane<40)
    float4 acc = make_float4(0.f, 0.f, 0.f, 0.f);

    if (items <= CH) {
        // ---- pass A: logits into registers (2 tiles x 5 heads), per-head max, ea sum
        float rw[2][NH];
        float lm[NH];
#pragma unroll
        for (int h = 0; h < NH; h++) lm[h] = -3.0e38f;
        float eas = 0.f;
        int myy[2];
#pragma unroll
        for (int t = 0; t < 2; t++) {
            int i = lane + 64 * t;
            if (i < deg) {
                uint4 rec = erec[s0 + i];
                int src = (int)rec.x;
                float eav = __uint_as_float(rec.z);
                isrc_sh[i] = src;
                myy[t] = (int)rec.y;
                eas += eav;
                const float* ap = als + (size_t)src * ALS8;
                float4 a4 = *reinterpret_cast<const float4*>(ap);
                float a5 = ap[4];
                float asv[5] = {a4.x, a4.y, a4.z, a4.w, a5};
#pragma unroll
                for (int h = 0; h < NH; h++) {
                    float r = lrelu(asv[h] + adr[h] + eav * ser[h], 0.2f);
                    rw[t][h] = r;
                    lm[h] = fmaxf(lm[h], r);
                }
            }
        }
#pragma unroll
        for (int o = 1; o < 64; o <<= 1) {
#pragma unroll
            for (int h = 0; h < NH; h++) lm[h] = fmaxf(lm[h], __shfl_xor(lm[h], o, 64));
            eas += __shfl_xor(eas, o, 64);
        }
        float emean = eas / fmaxf((float)deg, 1.f);
        float m[NH], rs[NH];
        {
            const float* ap = als + (size_t)n * ALS8;
            float4 a4 = *reinterpret_cast<const float4*>(ap);
            float a5 = ap[4];
            float asv[5] = {a4.x, a4.y, a4.z, a4.w, a5};
#pragma unroll
            for (int h = 0; h < NH; h++) {
                rs[h] = lrelu(asv[h] + adr[h] + emean * ser[h], 0.2f);
                m[h] = fmaxf(lm[h], rs[h]);
            }
        }
        // ---- pass B: exp in registers + sum
        float ls[NH] = {0.f, 0.f, 0.f, 0.f, 0.f};
#pragma unroll
        for (int t = 0; t < 2; t++) {
            int i = lane + 64 * t;
            if (i < deg) {
#pragma unroll
                for (int h = 0; h < NH; h++) {
                    float w = expf(rw[t][h] - m[h]);
                    rw[t][h] = w;
                    ls[h] += w;
                }
            } else if (i == deg) {          // self-loop owner lane
                isrc_sh[i] = n;
#pragma unroll
                for (int h = 0; h < NH; h++) {
                    float w = expf(rs[h] - m[h]);
                    rw[t][h] = w;
                    ls[h] += w;
                }
            }
        }
#pragma unroll
        for (int o = 1; o < 64; o <<= 1) {
#pragma unroll
            for (int h = 0; h < NH; h++) ls[h] += __shfl_xor(ls[h], o, 64);
        }
        float dinv[NH];
#pragma unroll
        for (int h = 0; h < NH; h++) dinv[h] = 1.f / ls[h];
        // ---- normalize: final weights -> LDS + alpha writeback
#pragma unroll
        for (int t = 0; t < 2; t++) {
            int i = lane + 64 * t;
            if (i < items) {
                int opos = (i < deg) ? myy[t] : (EE + n);
#pragma unroll
                for (int h = 0; h < NH; h++) {
                    float w = rw[t][h] * dinv[h];
                    w_sh[i * NH + h] = w;
                    alpha_out[(size_t)opos * NH + h] = w;
                }
            }
        }
        __syncthreads();                                   // [barrier #1 of 1]
        // ---- pass C: 4-deep pipelined fp16 gather (lanes 0..39, 8B/lane)
        if (lane < 40) {
            for (int i0 = 0; i0 < items; i0 += 4) {
                float wv[4];
                uint2 hv[4];
#pragma unroll
                for (int j = 0; j < 4; j++) {
                    int i = i0 + j;
                    bool ok = i < items;
                    int ii = ok ? i : 0;
                    wv[j] = ok ? w_sh[ii * NH + hd] : 0.f;
                    hv[j] = *reinterpret_cast<const uint2*>(
                        &hfeat[(size_t)isrc_sh[ii] * HC + c0]);
                }
#pragma unroll
                for (int j = 0; j < 4; j++) {
                    float4 hf = h8_to_f4(hv[j]);
                    acc.x += wv[j] * hf.x; acc.y += wv[j] * hf.y;
                    acc.z += wv[j] * hf.z; acc.w += wv[j] * hf.w;
                }
            }
        }
    } else {
        // ---- slow path (deg >= CH): streaming recompute, no LDS
        float lm[NH];
#pragma unroll
        for (int h = 0; h < NH; h++) lm[h] = -3.0e38f;
        float eas = 0.f;
        for (int i = lane; i < deg; i += 64) {
            uint4 rec = erec[s0 + i];
            int src = (int)rec.x;
            float eav = __uint_as_float(rec.z);
            eas += eav;
            const float* ap = als + (size_t)src * ALS8;
            float4 a4 = *reinterpret_cast<const float4*>(ap);
            float a5 = ap[4];
            float asv[5] = {a4.x, a4.y, a4.z, a4.w, a5};
#pragma unroll
            for (int h = 0; h < NH; h++) {
                float r = lrelu(asv[h] + adr[h] + eav * ser[h], 0.2f);
                lm[h] = fmaxf(lm[h], r);
            }
        }
#pragma unroll
        for (int o = 1; o < 64; o <<= 1) {
#pragma unroll
            for (int h = 0; h < NH; h++) lm[h] = fmaxf(lm[h], __shfl_xor(lm[h], o, 64));
            eas += __shfl_xor(eas, o, 64);
        }
        float emean = eas / fmaxf((float)deg, 1.f);
        float m[NH], rs[NH];
        {
            const float* ap = als + (size_t)n * ALS8;
#pragma unroll
            for (int h = 0; h < NH; h++) {
                rs[h] = lrelu(ap[h] + adr[h] + emean * ser[h], 0.2f);
                m[h] = fmaxf(lm[h], rs[h]);
            }
        }
        float ls[NH] = {0.f, 0.f, 0.f, 0.f, 0.f};
        for (int i = lane; i < items; i += 64) {
            int src; float eav;
            if (i < deg) { uint4 rec = erec[s0 + i]; src = (int)rec.x; eav = __uint_as_float(rec.z); }
            else         { src = n; eav = emean; }
            const float* ap = als + (size_t)src * ALS8;
#pragma unroll
            for (int h = 0; h < NH; h++) {
                float r = lrelu(ap[h] + adr[h] + eav * ser[h], 0.2f);
                ls[h] += expf(r - m[h]);
            }
        }
#pragma unroll
        for (int o = 1; o < 64; o <<= 1) {
#pragma unroll
            for (int h = 0; h < NH; h++) ls[h] += __shfl_xor(ls[h], o, 64);
        }
        float dinv[NH];
#pragma unroll
        for (int h = 0; h < NH; h++) dinv[h] = 1.f / ls[h];
        __syncthreads();                                   // [barrier #1 of 1]
        for (int i = lane; i < items; i += 64) {
            int src; float eav; int opos;
            if (i < deg) { uint4 rec = erec[s0 + i]; src = (int)rec.x; eav = __uint_as_float(rec.z); opos = (int)rec.y; }
            else         { src = n; eav = emean; opos = EE + n; }
            const float* ap = als + (size_t)src * ALS8;
#pragma unroll
            for (int h = 0; h < NH; h++) {
                float r = lrelu(ap[h] + adr[h] + eav * ser[h], 0.2f);
                alpha_out[(size_t)opos * NH + h] = expf(r - m[h]) * dinv[h];
            }
        }
        if (lane < 40) {
            for (int i = 0; i < items; i++) {
                int src; float eav;
                if (i < deg) { uint4 rec = erec[s0 + i]; src = (int)rec.x; eav = __uint_as_float(rec.z); }
                else         { src = n; eav = emean; }
                float r = lrelu(als[(size_t)src * ALS8 + hd] + adr[hd] + eav * ser[hd], 0.2f);
                float w = expf(r - m[hd]) * dinv[hd];
                uint2 hv = *reinterpret_cast<const uint2*>(
                    &hfeat[(size_t)src * HC + c0]);
                float4 hf = h8_to_f4(hv);
                acc.x += w * hf.x; acc.y += w * hf.y;
                acc.z += w * hf.z; acc.w += w * hf.w;
            }
        }
    }

    // ---- bias + lrelu + fused LayerNorm across 160 channels (wave butterfly)
    float4 v = make_float4(0.f, 0.f, 0.f, 0.f);
    float p1 = 0.f, p2 = 0.f;
    if (lane < 40) {
        const float4 b4 = *reinterpret_cast<const float4*>(&bias[c0]);
        v.x = lrelu(acc.x + b4.x, 0.01f);
        v.y = lrelu(acc.y + b4.y, 0.01f);
        v.z = lrelu(acc.z + b4.z, 0.01f);
        v.w = lrelu(acc.w + b4.w, 0.01f);
        p1 = v.x + v.y + v.z + v.w;
        p2 = v.x * v.x + v.y * v.y + v.z * v.z + v.w * v.w;
    }
#pragma unroll
    for (int o = 1; o < 64; o <<= 1) {
        p1 += __shfl_xor(p1, o, 64);
        p2 += __shfl_xor(p2, o, 64);
    }
    float mean = p1 * (1.f / (float)HC);
    float var = p2 * (1.f / (float)HC) - mean * mean;
    float rstd = rsqrtf(var + 1e-5f);
    if (lane < 40) {
        const float4 g4 = *reinterpret_cast<const float4*>(&g_ln[c0]);
        const float4 bb = *reinterpret_cast<const float4*>(&b_ln[c0]);
        float4 o4;
        o4.x = (v.x - mean) * rstd * g4.x + bb.x;
        o4.y = (v.y - mean) * rstd * g4.y + bb.y;
        o4.z = (v.z - mean) * rstd * g4.z + bb.z;
        o4.w = (v.w - mean) * rstd * g4.w + bb.w;
        *reinterpret_cast<float4*>(&x_out[(size_t)n * HC + c0]) = o4;
    }
}

// -------- x3 = lrelu(x2 @ mw + mb); 64x160 register-blocked; fused pooled sums
__global__ __launch_bounds__(256) void gemm3_kernel(const float* __restrict__ A,
                                                    const float* __restrict__ W,
                                                    const float* __restrict__ bias,
                                                    const int* __restrict__ batch,
                                                    float* __restrict__ x3,
                                                    float* __restrict__ psum) {
    __shared__ float As[32 * 64];
    __shared__ float Bs[32 * 160];
    __shared__ int bt[64];
    const int tid = threadIdx.x;
    const int base = blockIdx.x * 64;
    const int tc = tid & 31, tr = tid >> 5;
    const int srow = tid >> 2, skq = tid & 3;
    const bool rowok = (base + srow) < NN;
    const float* arow = A + (size_t)(base + srow) * HC;

    float acc[8][5];
#pragma unroll
    for (int r = 0; r < 8; r++)
#pragma unroll
        for (int c = 0; c < 5; c++) acc[r][c] = 0.f;

    for (int k0 = 0; k0 < HC; k0 += 32) {
        __syncthreads();
        float4 av0 = make_float4(0.f, 0.f, 0.f, 0.f), av1 = av0;
        if (rowok) {
            av0 = *reinterpret_cast<const float4*>(arow + k0 + skq * 4);
            av1 = *reinterpret_cast<const float4*>(arow + k0 + 16 + skq * 4);
        }
        As[(skq * 4 + 0) * 64 + srow] = av0.x;
        As[(skq * 4 + 1) * 64 + srow] = av0.y;
        As[(skq * 4 + 2) * 64 + srow] = av0.z;
        As[(skq * 4 + 3) * 64 + srow] = av0.w;
        As[(skq * 4 + 16) * 64 + srow] = av1.x;
        As[(skq * 4 + 17) * 64 + srow] = av1.y;
        As[(skq * 4 + 18) * 64 + srow] = av1.z;
        As[(skq * 4 + 19) * 64 + srow] = av1.w;
#pragma unroll
        for (int i = 0; i < 5; i++) {
            int f = tid + 256 * i;
            int kk = f / 40, c4 = f - kk * 40;
            *reinterpret_cast<float4*>(&Bs[kk * 160 + c4 * 4]) =
                *reinterpret_cast<const float4*>(&W[(size_t)(k0 + kk) * HC + c4 * 4]);
        }
        if (k0 == 0 && tid < 64)
            bt[tid] = batch[(base + tid < NN) ? (base + tid) : (NN - 1)];
        __syncthreads();
#pragma unroll 8
        for (int k = 0; k < 32; k++) {
            const float4 a0 = *reinterpret_cast<const float4*>(&As[k * 64 + tr * 8]);
            const float4 a1 = *reinterpret_cast<const float4*>(&As[k * 64 + tr * 8 + 4]);
            const float b0 = Bs[k * 160 + tc];
            const float b1 = Bs[k * 160 + tc + 32];
            const float b2 = Bs[k * 160 + tc + 64];
            const float b3 = Bs[k * 160 + tc + 96];
            const float b4 = Bs[k * 160 + tc + 128];
            ROWFMA(0, a0.x) ROWFMA(1, a0.y) ROWFMA(2, a0.z) ROWFMA(3, a0.w)
            ROWFMA(4, a1.x) ROWFMA(5, a1.y) ROWFMA(6, a1.z) ROWFMA(7, a1.w)
        }
    }
    float bj[5];
#pragma unroll
    for (int ci = 0; ci < 5; ci++) bj[ci] = bias[tc + 32 * ci];
    float run[5] = {0.f, 0.f, 0.f, 0.f, 0.f};
    int g = bt[tr * 8];
#pragma unroll
    for (int r = 0; r < 8; r++) {
        int grow = base + tr * 8 + r;
        bool ok = grow < NN;
        float vv[5];
#pragma unroll
        for (int ci = 0; ci < 5; ci++) vv[ci] = lrelu(acc[r][ci] + bj[ci], 0.01f);
        if (ok) {
            float* op = x3 + (size_t)grow * HC + tc;
            op[0] = vv[0]; op[32] = vv[1]; op[64] = vv[2]; op[96] = vv[3]; op[128] = vv[4];
        }
        int gb = bt[tr * 8 + r];
        if (gb != g) {
#pragma unroll
            for (int ci = 0; ci < 5; ci++) {
                atomicAdd(&psum[g * HC + tc + 32 * ci], run[ci]);
                run[ci] = 0.f;
            }
            g = gb;
        }
        if (ok) {
#pragma unroll
            for (int ci = 0; ci < 5; ci++) run[ci] += vv[ci];
        }
    }
#pragma unroll
    for (int ci = 0; ci < 5; ci++) atomicAdd(&psum[g * HC + tc + 32 * ci], run[ci]);
}

__global__ void pooldiv_kernel(const float* __restrict__ psum, const int* __restrict__ gcnt,
                               float* pooled_out) {
    int i = blockIdx.x * 256 + threadIdx.x;
    if (i < NG * HC) pooled_out[i] = psum[i] / fmaxf((float)gcnt[i / HC], 1.f);
}

// ---------------------------------------------------------------------- launch
extern "C" void kernel_launch(void* const* d_in, const int* in_sizes, int n_in,
                              void* d_out, int out_size, void* d_ws, size_t ws_size,
                              hipStream_t stream) {
    const float* x    = (const float*)d_in[0];
    const int*   ei   = (const int*)d_in[1];
    const float* ea   = (const float*)d_in[2];
    const int*   batch= (const int*)d_in[3];
    const float* w1   = (const float*)d_in[4];
    const float* we1  = (const float*)d_in[5];
    const float* as1  = (const float*)d_in[6];
    const float* ad1  = (const float*)d_in[7];
    const float* ae1  = (const float*)d_in[8];
    const float* b1   = (const float*)d_in[9];
    const float* w2   = (const float*)d_in[10];
    const float* we2  = (const float*)d_in[11];
    const float* as2  = (const float*)d_in[12];
    const float* ad2  = (const float*)d_in[13];
    const float* ae2  = (const float*)d_in[14];
    const float* b2   = (const float*)d_in[15];
    const float* ln1g = (const float*)d_in[16];
    const float* ln1b = (const float*)d_in[17];
    const float* ln2g = (const float*)d_in[18];
    const float* ln2b = (const float*)d_in[19];
    const float* mw   = (const float*)d_in[20];
    const float* mb   = (const float*)d_in[21];

    float* out = (float*)d_out;
    float* x12 = out;                                 // x1/x2 scratch in x3 region
    float* pooled_out = out + (size_t)NN * HC;
    float* a1 = pooled_out + NG * HC;
    float* a2 = a1 + (size_t)(EE + NN) * NH;

    char* wp = (char*)d_ws;
    auto alloc = [&](size_t bytes) {
        void* p = (void*)wp;
        wp += (bytes + 255) & ~(size_t)255;
        return p;
    };
    // hbuf region kept at 32MB so hist_g (8MB) + base_g (16MB) overlay still fits;
    // fp16 h uses only the first 16MB.
    __half* hbuf = (__half*)alloc((size_t)NN * HC * 4);
    unsigned*       hist_g = (unsigned*)hbuf;                       // 8 MB
    unsigned short* base_g = (unsigned short*)((char*)hbuf + 8 * 1024 * 1024); // 16 MB
    uint4* erec  = (uint4*)alloc((size_t)EE * 16);       // 12.8 MB
    float* als   = (float*)alloc((size_t)NN * ALS8 * 4); // padded al_s
    float* ald   = (float*)alloc((size_t)NN * NH * 4);
    int*   deg   = (int*)alloc((size_t)NN * 4);
    int*   soff  = (int*)alloc((size_t)(NN + 1) * 4);
    float* sbuf  = (float*)alloc(64);
    float* psum  = (float*)alloc((size_t)NG * HC * 4);
    int*   gcnt  = (int*)alloc((size_t)NG * 4);
    int*   bsum  = (int*)alloc(256 * 4);
    int*   boff  = (int*)alloc(256 * 4);

    prep_kernel<<<40, 256, 0, stream>>>(batch, psum, gcnt);
    hist_kernel<<<NB, 256, 0, stream>>>(ei, hist_g);
    sscan_kernel<<<49, 256, 0, stream>>>(hist_g, base_g, deg);
    scan1_kernel<<<196, 256, 0, stream>>>(deg, bsum);
    scan2_kernel<<<1, 256, 0, stream>>>(bsum, boff);
    scan3_kernel<<<196, 256, 0, stream>>>(deg, boff, soff);
    scatter_kernel<<<NB, 256, 0, stream>>>(ei, ea, base_g, soff, erec);
    preps_kernel<<<1, 64, 0, stream>>>(we1, ae1, we2, ae2, sbuf);

    gemm_kernel<128><<<782, 256, 0, stream>>>(x, w1, as1, ad1, hbuf, als, ald);
    aggregate_kernel<<<12500, 256, 0, stream>>>(soff, erec, hbuf, als, ald,
                                                sbuf, b1, ln1g, ln1b, a1, x12);

    gemm_kernel<160><<<782, 256, 0, stream>>>(x12, w2, as2, ad2, hbuf, als, ald);
    aggregate_kernel<<<12500, 256, 0, stream>>>(soff, erec, hbuf, als, ald,
                                                sbuf + 5, b2, ln2g, ln2b, a2, x12);

    gemm3_kernel<<<782, 256, 0, stream>>>(x12, mw, mb, batch, out, psum);
    pooldiv_kernel<<<40, 256, 0, stream>>>(psum, gcnt, pooled_out);
}